// Round 1
// baseline (174.871 us; speedup 1.0000x reference)
//
#include <hip/hip_runtime.h>
#include <hip/hip_bf16.h>
#include <stdint.h>

typedef unsigned short u16;
typedef __attribute__((ext_vector_type(8))) short short8;
typedef __attribute__((ext_vector_type(4))) float f32x4;
typedef __attribute__((ext_vector_type(4))) unsigned int u32x4;

#define CC    128
#define WW    48
#define HW2   2304      // 48*48
#define NHW   46
#define NQ    2116      // 46*46
#define MP    2176      // padded M (17*128)
#define NPK   2176      // per-candidate-set padded rows
#define NTOT  4352      // 2*2176
#define KK    1152      // 128*9
#define NGRP  144       // 16B groups per K row (1152*2/16)
#define NHALF 68        // 34 N-tiles * 2 wave-halves
#define BATCH 2
#define TOPKC 2

__device__ __forceinline__ u16 f2bf(float f) {
  union { float f; unsigned u; } x; x.f = f;
  unsigned r = (x.u + 0x7fffu + ((x.u >> 16) & 1u)) >> 16;
  return (u16)r;
}

// ---------------- kernel 1: per-pixel inverse channel norms ----------------
__global__ void k_invnorm(const float* __restrict__ pred, const float* __restrict__ targ,
                          float* __restrict__ invp, float* __restrict__ invt) {
  int idx = blockIdx.x * 256 + threadIdx.x;
  const int total = (BATCH + BATCH * TOPKC) * HW2;   // 13824
  if (idx >= total) return;
  int img = idx / HW2;
  int pix = idx - img * HW2;
  const float* src; float* dst;
  if (img < BATCH) { src = pred + (size_t)img * CC * HW2; dst = invp + img * HW2; }
  else { int t = img - BATCH; src = targ + (size_t)t * CC * HW2; dst = invt + t * HW2; }
  float s = 0.f;
  for (int c = 0; c < CC; ++c) { float v = src[(size_t)c * HW2 + pix]; s += v * v; }
  dst[pix] = 1.0f / fmaxf(sqrtf(s), 1e-12f);
}

// ------------- kernel 2/3: im2col of normalized images, bf16, pre-swizzled -------------
// Row layout: row r holds K=1152 bf16 = 144 16B-groups. Stored group g holds source
// k-group (g ^ (r & 3)) so that after linear global_load_lds staging into [row][64B]
// LDS tiles, the GEMM reads with the matching XOR and gets bank-spread addresses.
__global__ void k_im2col_a(const float* __restrict__ pred, const float* __restrict__ invp,
                           u16* __restrict__ Ab) {
  int idx = blockIdx.x * 256 + threadIdx.x;          // over BATCH*MP*NGRP
  int g  = idx % NGRP;
  int qp = (idx / NGRP) % MP;
  int b  = idx / (NGRP * MP);
  unsigned pack[4] = {0u, 0u, 0u, 0u};
  if (qp < NQ) {
    int qy = qp / NHW, qx = qp - qy * NHW;
    int gl = g ^ (qp & 3);
    const float* img = pred + (size_t)b * CC * HW2;
    const float* inv = invp + (size_t)b * HW2;
    #pragma unroll
    for (int e = 0; e < 8; ++e) {
      int k = gl * 8 + e;
      int c = k / 9;
      int s = k - 9 * c;
      int di = s / 3, dj = s - 3 * di;
      int y = qy + di, x = qx + dj;
      float v = img[(size_t)c * HW2 + y * WW + x] * inv[y * WW + x];
      pack[e >> 1] |= ((unsigned)f2bf(v)) << ((e & 1) * 16);
    }
  }
  u32x4 o; o.x = pack[0]; o.y = pack[1]; o.z = pack[2]; o.w = pack[3];
  *reinterpret_cast<u32x4*>(Ab + (size_t)idx * 8) = o;
}

__global__ void k_im2col_b(const float* __restrict__ targ, const float* __restrict__ invt,
                           u16* __restrict__ Bb) {
  int idx = blockIdx.x * 256 + threadIdx.x;          // over BATCH*NTOT*NGRP
  int g  = idx % NGRP;
  int np = (idx / NGRP) % NTOT;
  int b  = idx / (NGRP * NTOT);
  int kc = np / NPK;
  int ns = np - kc * NPK;
  unsigned pack[4] = {0u, 0u, 0u, 0u};
  if (ns < NQ) {
    int ny = ns / NHW, nx = ns - ny * NHW;
    int gl = g ^ (np & 3);
    const float* img = targ + (size_t)(b * TOPKC + kc) * CC * HW2;
    const float* inv = invt + (size_t)(b * TOPKC + kc) * HW2;
    #pragma unroll
    for (int e = 0; e < 8; ++e) {
      int k = gl * 8 + e;
      int c = k / 9;
      int s = k - 9 * c;
      int di = s / 3, dj = s - 3 * di;
      int y = ny + di, x = nx + dj;
      float v = img[(size_t)c * HW2 + y * WW + x] * inv[y * WW + x];
      pack[e >> 1] |= ((unsigned)f2bf(v)) << ((e & 1) * 16);
    }
  }
  u32x4 o; o.x = pack[0]; o.y = pack[1]; o.z = pack[2]; o.w = pack[3];
  *reinterpret_cast<u32x4*>(Bb + (size_t)idx * 8) = o;
}

// ---------------- kernel 4: 128x128 bf16 MFMA GEMM + fused row-max/argmax ----------------
__global__ __launch_bounds__(256) void k_gemm(const u16* __restrict__ Ab, const u16* __restrict__ Bb,
                                              float* __restrict__ valp, int* __restrict__ idxp) {
  __shared__ u16 sA[2][128 * 32];
  __shared__ u16 sB[2][128 * 32];
  const int tn = blockIdx.x, tm = blockIdx.y, b = blockIdx.z;
  const int tid = threadIdx.x;
  const int lane = tid & 63;
  const int wid = tid >> 6;
  const int wm = wid >> 1, wn = wid & 1;
  const int r15 = lane & 15, g16 = lane >> 4;

  const u16* Abase = Ab + ((size_t)b * MP + (size_t)tm * 128) * KK;
  const u16* Bbase = Bb + ((size_t)b * NTOT + (size_t)tn * 128) * KK;

  const int srow = lane >> 2;          // 0..15
  const int scol = (lane & 3) * 8;     // ushort offset in row: 0,8,16,24

  f32x4 acc[4][4];
  const f32x4 z4 = {0.f, 0.f, 0.f, 0.f};
  #pragma unroll
  for (int i = 0; i < 4; ++i)
    #pragma unroll
    for (int j = 0; j < 4; ++j) acc[i][j] = z4;

  auto stage = [&](int buf, int kt) {
    #pragma unroll
    for (int i = 0; i < 2; ++i) {
      int rb = wid * 32 + i * 16;
      const u16* g = Abase + (size_t)(rb + srow) * KK + kt * 32 + scol;
      u16* l = &sA[buf][rb * 32];
      __builtin_amdgcn_global_load_lds((const __attribute__((address_space(1))) unsigned int*)g,
                                       (__attribute__((address_space(3))) unsigned int*)l, 16, 0, 0);
    }
    #pragma unroll
    for (int i = 0; i < 2; ++i) {
      int rb = wid * 32 + i * 16;
      const u16* g = Bbase + (size_t)(rb + srow) * KK + kt * 32 + scol;
      u16* l = &sB[buf][rb * 32];
      __builtin_amdgcn_global_load_lds((const __attribute__((address_space(1))) unsigned int*)g,
                                       (__attribute__((address_space(3))) unsigned int*)l, 16, 0, 0);
    }
  };

  auto compute = [&](int buf) {
    short8 af[4], bfv[4];
    #pragma unroll
    for (int mi = 0; mi < 4; ++mi) {
      int row = wm * 64 + mi * 16 + r15;
      af[mi] = *(const short8*)&sA[buf][row * 32 + ((g16 ^ (row & 3)) * 8)];
    }
    #pragma unroll
    for (int ni = 0; ni < 4; ++ni) {
      int row = wn * 64 + ni * 16 + r15;
      bfv[ni] = *(const short8*)&sB[buf][row * 32 + ((g16 ^ (row & 3)) * 8)];
    }
    #pragma unroll
    for (int mi = 0; mi < 4; ++mi)
      #pragma unroll
      for (int ni = 0; ni < 4; ++ni)
        acc[mi][ni] = __builtin_amdgcn_mfma_f32_16x16x32_bf16(af[mi], bfv[ni], acc[mi][ni], 0, 0, 0);
  };

  stage(0, 0);
  __syncthreads();
  int cur = 0;
  for (int kt = 0; kt < 35; ++kt) {
    stage(cur ^ 1, kt + 1);
    compute(cur);
    __syncthreads();
    cur ^= 1;
  }
  compute(cur);

  // fused epilogue: per output row, max+first-argmax over this wave's 64 columns
  #pragma unroll
  for (int mi = 0; mi < 4; ++mi) {
    #pragma unroll
    for (int reg = 0; reg < 4; ++reg) {
      float bv = -3.0e38f; int bi = 0x7fffffff;
      #pragma unroll
      for (int ni = 0; ni < 4; ++ni) {
        float v = acc[mi][ni][reg];
        int ci = ni * 16 + r15;
        bool take = (v > bv) || (v == bv && ci < bi);
        bv = take ? v : bv;
        bi = take ? ci : bi;
      }
      #pragma unroll
      for (int off = 1; off < 16; off <<= 1) {
        float ov = __shfl_xor(bv, off, 64);
        int   oi = __shfl_xor(bi, off, 64);
        bool take = (ov > bv) || (ov == bv && oi < bi);
        bv = take ? ov : bv;
        bi = take ? oi : bi;
      }
      if (r15 == 0) {
        int q = tm * 128 + wm * 64 + mi * 16 + g16 * 4 + reg;
        int h = tn * 2 + wn;
        size_t o = ((size_t)b * NHALF + h) * MP + q;
        valp[o] = bv;
        idxp[o] = tn * 128 + wn * 64 + bi;
      }
    }
  }
}

// ---------------- kernel 5: reduce partial maxima over the 68 column-halves ----------------
__global__ void k_argmax(const float* __restrict__ valp, const int* __restrict__ idxp,
                         int* __restrict__ best) {
  int idx = blockIdx.x * 256 + threadIdx.x;   // over BATCH*MP
  if (idx >= BATCH * MP) return;
  int b = idx / MP, q = idx - b * MP;
  if (q >= NQ) return;
  float bv = -3.0e38f; int bi = 0;
  for (int h = 0; h < NHALF; ++h) {
    size_t o = ((size_t)b * NHALF + h) * MP + q;
    float v = valp[o];
    if (v > bv) { bv = v; bi = idxp[o]; }     // strict > keeps first occurrence (k-major order)
  }
  best[b * NQ + q] = bi;
}

// ---------------- kernel 6: per-query MSE partial sums (raw patches) ----------------
__global__ void k_mse(const float* __restrict__ pred, const float* __restrict__ targ,
                      const int* __restrict__ best, float* __restrict__ msep) {
  int q = blockIdx.x;   // 0..NQ-1
  int b = blockIdx.y;   // 0..1
  int t = threadIdx.x;
  int np = best[b * NQ + q];
  int kc = np / NPK;
  int ns = np - kc * NPK;
  ns = ns < NQ ? ns : (NQ - 1);
  int qy = q / NHW, qx = q - qy * NHW;
  int ny = ns / NHW, nx = ns - ny * NHW;
  const float* P = pred + (size_t)b * CC * HW2;
  const float* T = targ + (size_t)(b * TOPKC + kc) * CC * HW2;
  float s = 0.f;
  for (int i = t; i < CC * 9; i += 256) {
    int c = i / 9, sp = i - 9 * c;
    int di = sp / 3, dj = sp - 3 * di;
    float d = P[(size_t)c * HW2 + (qy + di) * WW + qx + dj]
            - T[(size_t)c * HW2 + (ny + di) * WW + nx + dj];
    s += d * d;
  }
  __shared__ float red[256];
  red[t] = s; __syncthreads();
  for (int st = 128; st > 0; st >>= 1) { if (t < st) red[t] += red[t + st]; __syncthreads(); }
  if (t == 0) msep[b * NQ + q] = red[0];
}

// ---------------- kernel 7: final deterministic reduction ----------------
__global__ void k_final(const float* __restrict__ msep, float* __restrict__ out) {
  int t = threadIdx.x;
  float s = 0.f;
  for (int i = t; i < BATCH * NQ; i += 256) s += msep[i];
  __shared__ float red[256];
  red[t] = s; __syncthreads();
  for (int st = 128; st > 0; st >>= 1) { if (t < st) red[t] += red[t + st]; __syncthreads(); }
  if (t == 0) out[0] = red[0] * (1.0f / 4875264.0f);   // 2*2116*128*9
}

extern "C" void kernel_launch(void* const* d_in, const int* in_sizes, int n_in,
                              void* d_out, int out_size, void* d_ws, size_t ws_size,
                              hipStream_t stream) {
  const float* pred = (const float*)d_in[0];
  const float* targ = (const float*)d_in[1];
  char* ws = (char*)d_ws;

  size_t offA    = 0;
  size_t offB    = offA + (size_t)BATCH * MP * KK * 2;      // A: 10,027,008 B
  size_t offV    = offB + (size_t)BATCH * NTOT * KK * 2;    // B: 20,054,016 B
  size_t offI    = offV + (size_t)BATCH * NHALF * MP * 4;
  size_t offP    = offI + (size_t)BATCH * NHALF * MP * 4;
  size_t offT    = offP + (size_t)BATCH * HW2 * 4;
  size_t offBest = offT + (size_t)BATCH * TOPKC * HW2 * 4;
  size_t offM    = offBest + (size_t)BATCH * NQ * 4;

  u16*   Ab   = (u16*)(ws + offA);
  u16*   Bb   = (u16*)(ws + offB);
  float* valp = (float*)(ws + offV);
  int*   idxp = (int*)(ws + offI);
  float* invp = (float*)(ws + offP);
  float* invt = (float*)(ws + offT);
  int*   best = (int*)(ws + offBest);
  float* msep = (float*)(ws + offM);

  k_invnorm<<<54, 256, 0, stream>>>(pred, targ, invp, invt);
  k_im2col_a<<<2448, 256, 0, stream>>>(pred, invp, Ab);      // 2*2176*144 threads
  k_im2col_b<<<4896, 256, 0, stream>>>(targ, invt, Bb);      // 2*4352*144 threads
  k_gemm<<<dim3(34, 17, 2), 256, 0, stream>>>(Ab, Bb, valp, idxp);
  k_argmax<<<17, 256, 0, stream>>>(valp, idxp, best);
  k_mse<<<dim3(NQ, 2), 256, 0, stream>>>(pred, targ, best, msep);
  k_final<<<1, 256, 0, stream>>>(msep, (float*)d_out);
}

// Round 2
// 147.260 us; speedup vs baseline: 1.1875x; 1.1875x over previous
//
#include <hip/hip_runtime.h>
#include <hip/hip_bf16.h>

typedef unsigned short u16;
typedef __attribute__((ext_vector_type(8))) short short8;
typedef __attribute__((ext_vector_type(4))) float f32x4;
typedef __attribute__((ext_vector_type(4))) unsigned int u32x4;

#define CC    128
#define WW    48
#define HW2   2304      // 48*48
#define NHW   46
#define NQ    2116      // 46*46
#define MROWS 2176      // padded M rows per batch (17*128)
#define NPK   2176      // rows per candidate set inside B
#define NTOT  4352      // 17*256
#define KK    1152      // 128*9
#define NKT   18        // K-tiles of 64
#define NHALF 68        // 17 N-tiles * 4 wave-columns
#define BATCH 2

__device__ __forceinline__ u16 f2bf(float f) {
  union { float f; unsigned u; } x; x.f = f;
  unsigned r = (x.u + 0x7fffu + ((x.u >> 16) & 1u)) >> 16;
  return (u16)r;
}

// ---- kernel 1: fused invnorm + im2col (bf16, pre-swizzled chunks), LDS-staged ----
// Row r of A/B holds K=1152 bf16 = 144 16B-chunks; stored chunk (kt*8+c) contains
// source k-chunk (kt*8 + (c ^ (r&7))) so the GEMM's linear global_load_lds staging
// plus XOR-on-read yields bank-spread ds_read_b128.
__global__ __launch_bounds__(256) void k_im2col(const float* __restrict__ pred,
                                                const float* __restrict__ targ,
                                                u16* __restrict__ Ab, u16* __restrict__ Bb) {
  const int img = blockIdx.y;       // 0..5 : 0-1 pred, 2-5 target
  const int qy  = blockIdx.x;       // 0..45 real rows, 46-47 pad writer
  const int tid = threadIdx.x;
  const bool isA = img < 2;
  const float* image;
  u16* out;
  int rkc = 0;
  if (isA) {
    image = pred + (size_t)img * CC * HW2;
    out = Ab + (size_t)img * MROWS * KK;
  } else {
    int t = img - 2;                // (b*2 + kc)
    rkc = (t & 1) * NPK;
    image = targ + (size_t)t * CC * HW2;
    out = Bb + (size_t)(t >> 1) * NTOT * KK;
  }

  if (qy >= NHW) {                  // zero the 60 pad rows (2116..2175 of this set)
    int p0 = rkc + NQ + (qy - NHW) * 30;
    const u32x4 z = {0u, 0u, 0u, 0u};
    for (int i = tid; i < 30 * 144; i += 256) {
      int rr = i / 144, g = i - rr * 144;
      *reinterpret_cast<u32x4*>(out + ((size_t)(p0 + rr) * KK + g * 8)) = z;
    }
    return;
  }

  __shared__ float sI[CC * 144];    // [c][di*48+x], 73728 B
  __shared__ float sInv[144];

  for (int ch = tid; ch < CC * 36; ch += 256) {   // 36 float4 per channel
    int c = ch / 36, rem = ch - c * 36, di = rem / 12, j = rem - di * 12;
    float4 v = *reinterpret_cast<const float4*>(&image[(size_t)c * HW2 + (qy + di) * WW + j * 4]);
    *reinterpret_cast<float4*>(&sI[c * 144 + di * 48 + j * 4]) = v;
  }
  __syncthreads();
  for (int p = tid; p < 144; p += 256) {
    float s = 0.f;
    for (int c = 0; c < CC; ++c) { float v = sI[c * 144 + p]; s += v * v; }
    sInv[p] = 1.0f / fmaxf(sqrtf(s), 1e-12f);
  }
  __syncthreads();

  const int rb = rkc + qy * NHW;
  for (int g = tid; g < NHW * 144; g += 256) {
    int qx = g / 144, gg = g - qx * 144;
    int r = rb + qx;
    int sc = (gg & ~7) | ((gg & 7) ^ (r & 7));   // pre-swizzled source chunk
    int k0 = sc * 8;
    unsigned pack[4] = {0u, 0u, 0u, 0u};
    #pragma unroll
    for (int e = 0; e < 8; ++e) {
      int k = k0 + e;
      int c = k / 9, s9 = k - 9 * c;
      int di = s9 / 3, dj = s9 - 3 * di;
      int pix = di * 48 + qx + dj;
      float v = sI[c * 144 + pix] * sInv[pix];
      pack[e >> 1] |= ((unsigned)f2bf(v)) << ((e & 1) * 16);
    }
    u32x4 o; o.x = pack[0]; o.y = pack[1]; o.z = pack[2]; o.w = pack[3];
    *reinterpret_cast<u32x4*>(out + ((size_t)r * KK + gg * 8)) = o;
  }
}

// ---- kernel 2: 128x256 bf16 MFMA GEMM, counted-vmcnt pipeline, fused argmax ----
__global__ __launch_bounds__(512, 2) void k_gemm(const u16* __restrict__ Ab, const u16* __restrict__ Bb,
                                                 float* __restrict__ valp, int* __restrict__ idxp) {
  __shared__ u16 sA[2][128 * 64];   // 32 KB
  __shared__ u16 sB[2][256 * 64];   // 64 KB
  const int tn = blockIdx.x, tm = blockIdx.y, b = blockIdx.z;
  const int tid = threadIdx.x, lane = tid & 63, wid = tid >> 6;
  const int wm = wid >> 2, wn = wid & 3;          // 2 M-waves x 4 N-waves
  const int r15 = lane & 15, g16 = lane >> 4;

  const u16* Abase = Ab + ((size_t)b * MROWS + (size_t)tm * 128) * KK;
  const u16* Bbase = Bb + ((size_t)b * NTOT + (size_t)tn * 256) * KK;

  const int lr = lane >> 3, lc = lane & 7;
  const u16* aSrc[2];
  #pragma unroll
  for (int i = 0; i < 2; ++i)
    aSrc[i] = Abase + (size_t)((wid * 2 + i) * 8 + lr) * KK + lc * 8;
  const u16* bSrc[4];
  #pragma unroll
  for (int i = 0; i < 4; ++i)
    bSrc[i] = Bbase + (size_t)((wid * 4 + i) * 8 + lr) * KK + lc * 8;

  f32x4 acc[4][4];
  const f32x4 z4 = {0.f, 0.f, 0.f, 0.f};
  #pragma unroll
  for (int i = 0; i < 4; ++i)
    #pragma unroll
    for (int j = 0; j < 4; ++j) acc[i][j] = z4;

  auto stage = [&](int buf, int kt) {              // 6 global_load_lds per thread
    #pragma unroll
    for (int i = 0; i < 2; ++i)
      __builtin_amdgcn_global_load_lds(
        (const __attribute__((address_space(1))) unsigned*)(aSrc[i] + kt * 64),
        (__attribute__((address_space(3))) unsigned*)&sA[buf][(wid * 2 + i) * 8 * 64], 16, 0, 0);
    #pragma unroll
    for (int i = 0; i < 4; ++i)
      __builtin_amdgcn_global_load_lds(
        (const __attribute__((address_space(1))) unsigned*)(bSrc[i] + kt * 64),
        (__attribute__((address_space(3))) unsigned*)&sB[buf][(wid * 4 + i) * 8 * 64], 16, 0, 0);
  };

  auto compute = [&](int buf) {
    #pragma unroll
    for (int ks = 0; ks < 2; ++ks) {
      short8 af[4], bfv[4];
      #pragma unroll
      for (int ni = 0; ni < 4; ++ni) {
        int row = wn * 64 + ni * 16 + r15;
        bfv[ni] = *reinterpret_cast<const short8*>(&sB[buf][row * 64 + (((ks * 4 + g16) ^ (row & 7)) * 8)]);
      }
      #pragma unroll
      for (int mi = 0; mi < 4; ++mi) {
        int row = wm * 64 + mi * 16 + r15;
        af[mi] = *reinterpret_cast<const short8*>(&sA[buf][row * 64 + (((ks * 4 + g16) ^ (row & 7)) * 8)]);
      }
      #pragma unroll
      for (int mi = 0; mi < 4; ++mi)
        #pragma unroll
        for (int ni = 0; ni < 4; ++ni)
          acc[mi][ni] = __builtin_amdgcn_mfma_f32_16x16x32_bf16(af[mi], bfv[ni], acc[mi][ni], 0, 0, 0);
    }
  };

  stage(0, 0);
  stage(1, 1);
  for (int kt = 0; kt < NKT - 1; ++kt) {
    asm volatile("s_waitcnt vmcnt(6)" ::: "memory");   // own buf[kt&1] loads landed
    __builtin_amdgcn_s_barrier();                      // everyone's landed
    __builtin_amdgcn_sched_barrier(0);
    compute(kt & 1);
    __builtin_amdgcn_s_barrier();                      // everyone done reading buf[kt&1]
    __builtin_amdgcn_sched_barrier(0);
    if (kt < NKT - 2) stage(kt & 1, kt + 2);
  }
  asm volatile("s_waitcnt vmcnt(0)" ::: "memory");
  __builtin_amdgcn_s_barrier();
  __builtin_amdgcn_sched_barrier(0);
  compute((NKT - 1) & 1);

  // fused epilogue: per row, max + first-wins argmax over this wave's 64 columns
  const int nb = tn * 256 + wn * 64;
  #pragma unroll
  for (int mi = 0; mi < 4; ++mi) {
    #pragma unroll
    for (int reg = 0; reg < 4; ++reg) {
      float bv = -3.0e38f; int bi = 0x7fffffff;
      #pragma unroll
      for (int ni = 0; ni < 4; ++ni) {
        int n = nb + ni * 16 + r15;
        int ns = n - (n >= NPK ? NPK : 0);
        float v = acc[mi][ni][reg];
        if (ns >= NQ) v = -3.0e38f;                    // mask pad columns
        bool take = (v > bv) || (v == bv && n < bi);
        bv = take ? v : bv;
        bi = take ? n : bi;
      }
      #pragma unroll
      for (int off = 1; off < 16; off <<= 1) {
        float ov = __shfl_xor(bv, off, 64);
        int   oi = __shfl_xor(bi, off, 64);
        bool take = (ov > bv) || (ov == bv && oi < bi);
        bv = take ? ov : bv;
        bi = take ? oi : bi;
      }
      if (r15 == 0) {
        int q = tm * 128 + wm * 64 + mi * 16 + g16 * 4 + reg;
        size_t o = ((size_t)b * NHALF + (tn * 4 + wn)) * MROWS + q;
        valp[o] = bv;
        idxp[o] = bi;
      }
    }
  }
}

// ---- kernel 3: wave-per-query argmax over 68 halves + raw-patch MSE ----
__global__ __launch_bounds__(256) void k_msearg(const float* __restrict__ pred, const float* __restrict__ targ,
                                                const float* __restrict__ valp, const int* __restrict__ idxp,
                                                float* __restrict__ msep) {
  int gw = (blockIdx.x * 256 + threadIdx.x) >> 6;
  int lane = threadIdx.x & 63;
  if (gw >= BATCH * NQ) return;
  int b = gw >= NQ ? 1 : 0;
  int q = gw - b * NQ;

  const float* vp = valp + (size_t)b * NHALF * MROWS + q;
  const int*   ip = idxp + (size_t)b * NHALF * MROWS + q;
  float bv = vp[(size_t)lane * MROWS];
  int   bi = ip[(size_t)lane * MROWS];
  if (lane < NHALF - 64) {
    float v1 = vp[(size_t)(64 + lane) * MROWS];
    int   i1 = ip[(size_t)(64 + lane) * MROWS];
    if (v1 > bv || (v1 == bv && i1 < bi)) { bv = v1; bi = i1; }
  }
  #pragma unroll
  for (int off = 1; off < 64; off <<= 1) {
    float ov = __shfl_xor(bv, off, 64);
    int   oi = __shfl_xor(bi, off, 64);
    bool take = (ov > bv) || (ov == bv && oi < bi);
    bv = take ? ov : bv;
    bi = take ? oi : bi;
  }
  int n = bi;
  int kc = n >= NPK ? 1 : 0;
  int ns = n - kc * NPK;
  ns = ns < NQ ? ns : NQ - 1;

  int qy = q / NHW, qx = q - qy * NHW;
  int ny = ns / NHW, nx = ns - ny * NHW;
  const float* P = pred + (size_t)b * CC * HW2;
  const float* T = targ + (size_t)(b * 2 + kc) * CC * HW2;
  float s = 0.f;
  for (int i = lane; i < CC * 9; i += 64) {
    int c = i / 9, sp = i - 9 * c;
    int di = sp / 3, dj = sp - 3 * di;
    float d = P[(size_t)c * HW2 + (qy + di) * WW + qx + dj]
            - T[(size_t)c * HW2 + (ny + di) * WW + nx + dj];
    s += d * d;
  }
  #pragma unroll
  for (int off = 1; off < 64; off <<= 1) s += __shfl_xor(s, off, 64);
  if (lane == 0) msep[gw] = s;
}

// ---- kernel 4: final deterministic reduction ----
__global__ void k_final(const float* __restrict__ msep, float* __restrict__ out) {
  int t = threadIdx.x;
  float s = 0.f;
  for (int i = t; i < BATCH * NQ; i += 256) s += msep[i];
  __shared__ float red[256];
  red[t] = s; __syncthreads();
  for (int st = 128; st > 0; st >>= 1) { if (t < st) red[t] += red[t + st]; __syncthreads(); }
  if (t == 0) out[0] = red[0] * (1.0f / 4875264.0f);   // 2*2116*128*9
}

extern "C" void kernel_launch(void* const* d_in, const int* in_sizes, int n_in,
                              void* d_out, int out_size, void* d_ws, size_t ws_size,
                              hipStream_t stream) {
  const float* pred = (const float*)d_in[0];
  const float* targ = (const float*)d_in[1];
  char* ws = (char*)d_ws;

  size_t offA = 0;
  size_t offB = offA + (size_t)BATCH * MROWS * KK * 2;      // 10,027,008
  size_t offV = offB + (size_t)BATCH * NTOT * KK * 2;       // 20,054,016
  size_t offI = offV + (size_t)BATCH * NHALF * MROWS * 4;   // 1,183,744
  size_t offM = offI + (size_t)BATCH * NHALF * MROWS * 4;   // 1,183,744

  u16*   Ab   = (u16*)(ws + offA);
  u16*   Bb   = (u16*)(ws + offB);
  float* valp = (float*)(ws + offV);
  int*   idxp = (int*)(ws + offI);
  float* msep = (float*)(ws + offM);

  k_im2col<<<dim3(48, 6), 256, 0, stream>>>(pred, targ, Ab, Bb);
  k_gemm<<<dim3(17, 17, 2), 512, 0, stream>>>(Ab, Bb, valp, idxp);
  k_msearg<<<dim3((BATCH * NQ + 3) / 4), 256, 0, stream>>>(pred, targ, valp, idxp, msep);
  k_final<<<1, 256, 0, stream>>>(msep, (float*)d_out);
}

// Round 3
// 135.283 us; speedup vs baseline: 1.2926x; 1.0885x over previous
//
#include <hip/hip_runtime.h>
#include <hip/hip_bf16.h>

typedef unsigned short u16;
typedef __attribute__((ext_vector_type(8))) short short8;
typedef __attribute__((ext_vector_type(4))) float f32x4;
typedef __attribute__((ext_vector_type(4))) unsigned int u32x4;

#define CC    128
#define WW    48
#define HW2   2304      // 48*48
#define NHW   46
#define NQ    2116      // 46*46
#define MROWS 2176      // padded M rows per batch (17*128)
#define NPK   2176      // rows per candidate set inside B
#define NTOT  4352      // 17*256
#define KK    1152      // 128*9
#define NKT   36        // K-tiles of 32
#define NHALF 68        // 17 N-tiles * 4 wave-columns
#define BATCH 2

__device__ __forceinline__ u16 f2bf(float f) {
  union { float f; unsigned u; } x; x.f = f;
  unsigned r = (x.u + 0x7fffu + ((x.u >> 16) & 1u)) >> 16;
  return (u16)r;
}

// ---- kernel 1: fused invnorm + im2col (bf16, pre-swizzled chunks), LDS-staged ----
// Row r holds K=1152 bf16 = 144 16B-chunks grouped in 36 K-tiles of 4 chunks.
// Within each 4-chunk group, stored position p contains source chunk p ^ ((r>>1)&3),
// so the GEMM's linear global_load_lds staging + XOR-on-read gives bank-spread
// ds_read_b128 (distinct banks for every aligned 8-lane phase group).
__global__ __launch_bounds__(256) void k_im2col(const float* __restrict__ pred,
                                                const float* __restrict__ targ,
                                                u16* __restrict__ Ab, u16* __restrict__ Bb) {
  const int img = blockIdx.y;       // 0..5 : 0-1 pred, 2-5 target
  const int qy  = blockIdx.x;       // 0..45 real rows, 46-47 pad writer
  const int tid = threadIdx.x;
  const bool isA = img < 2;
  const float* image;
  u16* out;
  int rkc = 0;
  if (isA) {
    image = pred + (size_t)img * CC * HW2;
    out = Ab + (size_t)img * MROWS * KK;
  } else {
    int t = img - 2;                // (b*2 + kc)
    rkc = (t & 1) * NPK;
    image = targ + (size_t)t * CC * HW2;
    out = Bb + (size_t)(t >> 1) * NTOT * KK;
  }

  if (qy >= NHW) {                  // zero the 60 pad rows (2116..2175 of this set)
    int p0 = rkc + NQ + (qy - NHW) * 30;
    const u32x4 z = {0u, 0u, 0u, 0u};
    for (int i = tid; i < 30 * 144; i += 256) {
      int rr = i / 144, g = i - rr * 144;
      *reinterpret_cast<u32x4*>(out + ((size_t)(p0 + rr) * KK + g * 8)) = z;
    }
    return;
  }

  __shared__ float sI[CC * 144];    // [c][di*48+x], 73728 B
  __shared__ float sInv[144];

  for (int ch = tid; ch < CC * 36; ch += 256) {   // 36 float4 per channel
    int c = ch / 36, rem = ch - c * 36, di = rem / 12, j = rem - di * 12;
    float4 v = *reinterpret_cast<const float4*>(&image[(size_t)c * HW2 + (qy + di) * WW + j * 4]);
    *reinterpret_cast<float4*>(&sI[c * 144 + di * 48 + j * 4]) = v;
  }
  __syncthreads();
  for (int p = tid; p < 144; p += 256) {
    float s = 0.f;
    for (int c = 0; c < CC; ++c) { float v = sI[c * 144 + p]; s += v * v; }
    sInv[p] = 1.0f / fmaxf(sqrtf(s), 1e-12f);
  }
  __syncthreads();

  const int rb = rkc + qy * NHW;
  for (int g = tid; g < NHW * 144; g += 256) {
    int qx = g / 144, gg = g - qx * 144;
    int r = rb + qx;
    int sc = (gg & ~3) | ((gg & 3) ^ ((r >> 1) & 3));   // pre-swizzled source chunk
    int k0 = sc * 8;
    unsigned pack[4] = {0u, 0u, 0u, 0u};
    #pragma unroll
    for (int e = 0; e < 8; ++e) {
      int k = k0 + e;
      int c = k / 9, s9 = k - 9 * c;
      int di = s9 / 3, dj = s9 - 3 * di;
      int pix = di * 48 + qx + dj;
      float v = sI[c * 144 + pix] * sInv[pix];
      pack[e >> 1] |= ((unsigned)f2bf(v)) << ((e & 1) * 16);
    }
    u32x4 o; o.x = pack[0]; o.y = pack[1]; o.z = pack[2]; o.w = pack[3];
    *reinterpret_cast<u32x4*>(out + ((size_t)r * KK + gg * 8)) = o;
  }
}

// ---- kernel 2: 128x256 bf16 MFMA GEMM, depth-3 single-barrier pipeline, fused argmax ----
__global__ __launch_bounds__(512, 4) void k_gemm(const u16* __restrict__ Ab, const u16* __restrict__ Bb,
                                                 float* __restrict__ valp, int* __restrict__ idxp) {
  __shared__ u16 sA[3][128 * 32];   // 3 x 8 KB
  __shared__ u16 sB[3][256 * 32];   // 3 x 16 KB  (72 KB total -> 2 blocks/CU)

  // XCD-aware bijective swizzle over 578 blocks (q=72, r=2), tm-fastest order
  const int w = blockIdx.x;
  const int xcd = w & 7, pos = w >> 3;
  const int swz = (xcd < 2 ? xcd * 73 : 2 * 73 + (xcd - 2) * 72) + pos;
  const int col = swz / 17;          // 0..33  (b*17 + tn)
  const int tm  = swz - col * 17;    // 0..16
  const int b   = col / 17;
  const int tn  = col - b * 17;

  const int tid = threadIdx.x, lane = tid & 63, wid = tid >> 6;
  const int wm = wid >> 2, wn = wid & 3;          // 2 M-waves x 4 N-waves
  const int r15 = lane & 15, g16 = lane >> 4;

  const u16* Abase = Ab + ((size_t)b * MROWS + (size_t)tm * 128) * KK;
  const u16* Bbase = Bb + ((size_t)b * NTOT + (size_t)tn * 256) * KK;

  // per-thread staging source (row, 16B-chunk); LDS dest is linear in tid
  const u16* aSrc = Abase + (size_t)(tid >> 2) * KK + (tid & 3) * 8;
  const u16* bSrc0 = Bbase + (size_t)(tid >> 2) * KK + (tid & 3) * 8;
  const u16* bSrc1 = Bbase + (size_t)((512 + tid) >> 2) * KK + (tid & 3) * 8;

  f32x4 acc[4][4];
  const f32x4 z4 = {0.f, 0.f, 0.f, 0.f};
  #pragma unroll
  for (int i = 0; i < 4; ++i)
    #pragma unroll
    for (int j = 0; j < 4; ++j) acc[i][j] = z4;

  auto stage = [&](int buf, int kt) {              // 3 global_load_lds per thread
    __builtin_amdgcn_global_load_lds(
      (const __attribute__((address_space(1))) unsigned*)(aSrc + kt * 32),
      (__attribute__((address_space(3))) unsigned*)&sA[buf][tid * 8], 16, 0, 0);
    __builtin_amdgcn_global_load_lds(
      (const __attribute__((address_space(1))) unsigned*)(bSrc0 + kt * 32),
      (__attribute__((address_space(3))) unsigned*)&sB[buf][tid * 8], 16, 0, 0);
    __builtin_amdgcn_global_load_lds(
      (const __attribute__((address_space(1))) unsigned*)(bSrc1 + kt * 32),
      (__attribute__((address_space(3))) unsigned*)&sB[buf][(512 + tid) * 8], 16, 0, 0);
  };

  auto compute = [&](int buf) {
    short8 af[4], bfv[4];
    #pragma unroll
    for (int ni = 0; ni < 4; ++ni) {
      int row = wn * 64 + ni * 16 + r15;
      bfv[ni] = *reinterpret_cast<const short8*>(&sB[buf][row * 32 + ((g16 ^ ((row >> 1) & 3)) * 8)]);
    }
    #pragma unroll
    for (int mi = 0; mi < 4; ++mi) {
      int row = wm * 64 + mi * 16 + r15;
      af[mi] = *reinterpret_cast<const short8*>(&sA[buf][row * 32 + ((g16 ^ ((row >> 1) & 3)) * 8)]);
    }
    __builtin_amdgcn_s_setprio(1);
    #pragma unroll
    for (int mi = 0; mi < 4; ++mi)
      #pragma unroll
      for (int ni = 0; ni < 4; ++ni)
        acc[mi][ni] = __builtin_amdgcn_mfma_f32_16x16x32_bf16(af[mi], bfv[ni], acc[mi][ni], 0, 0, 0);
    __builtin_amdgcn_s_setprio(0);
  };

  stage(0, 0);
  stage(1, 1);
  int buf = 0;
  for (int kt = 0; kt < NKT - 1; ++kt) {
    asm volatile("s_waitcnt vmcnt(3)" ::: "memory");   // tile kt landed (own loads)
    __builtin_amdgcn_s_barrier();                      // all waves: kt landed, kt-1 readers done
    __builtin_amdgcn_sched_barrier(0);
    if (kt + 2 < NKT) {
      int nb = buf + 2; if (nb >= 3) nb -= 3;
      stage(nb, kt + 2);
    }
    compute(buf);
    if (++buf == 3) buf = 0;
  }
  asm volatile("s_waitcnt vmcnt(0)" ::: "memory");
  __builtin_amdgcn_s_barrier();
  __builtin_amdgcn_sched_barrier(0);
  compute(buf);

  // fused epilogue: per row, max + first-wins argmax over this wave's 64 columns
  const int nb = tn * 256 + wn * 64;
  #pragma unroll
  for (int mi = 0; mi < 4; ++mi) {
    #pragma unroll
    for (int reg = 0; reg < 4; ++reg) {
      float bv = -3.0e38f; int bi = 0x7fffffff;
      #pragma unroll
      for (int ni = 0; ni < 4; ++ni) {
        int n = nb + ni * 16 + r15;
        int ns = n - (n >= NPK ? NPK : 0);
        float v = acc[mi][ni][reg];
        if (ns >= NQ) v = -3.0e38f;                    // mask pad columns
        bool take = (v > bv) || (v == bv && n < bi);
        bv = take ? v : bv;
        bi = take ? n : bi;
      }
      #pragma unroll
      for (int off = 1; off < 16; off <<= 1) {
        float ov = __shfl_xor(bv, off, 64);
        int   oi = __shfl_xor(bi, off, 64);
        bool take = (ov > bv) || (ov == bv && oi < bi);
        bv = take ? ov : bv;
        bi = take ? oi : bi;
      }
      if (r15 == 0) {
        int q = tm * 128 + wm * 64 + mi * 16 + g16 * 4 + reg;
        size_t o = ((size_t)b * MROWS + q) * NHALF + (tn * 4 + wn);
        valp[o] = bv;
        idxp[o] = bi;
      }
    }
  }
}

// ---- kernel 3: wave-per-query argmax over 68 halves + raw-patch MSE ----
__global__ __launch_bounds__(256) void k_msearg(const float* __restrict__ pred, const float* __restrict__ targ,
                                                const float* __restrict__ valp, const int* __restrict__ idxp,
                                                float* __restrict__ msep) {
  int gw = (blockIdx.x * 256 + threadIdx.x) >> 6;
  int lane = threadIdx.x & 63;
  if (gw >= BATCH * NQ) return;
  int b = gw >= NQ ? 1 : 0;
  int q = gw - b * NQ;

  const float* vp = valp + ((size_t)b * MROWS + q) * NHALF;
  const int*   ip = idxp + ((size_t)b * MROWS + q) * NHALF;
  float bv = vp[lane];
  int   bi = ip[lane];
  if (lane < NHALF - 64) {
    float v1 = vp[64 + lane];
    int   i1 = ip[64 + lane];
    if (v1 > bv || (v1 == bv && i1 < bi)) { bv = v1; bi = i1; }
  }
  #pragma unroll
  for (int off = 1; off < 64; off <<= 1) {
    float ov = __shfl_xor(bv, off, 64);
    int   oi = __shfl_xor(bi, off, 64);
    bool take = (ov > bv) || (ov == bv && oi < bi);
    bv = take ? ov : bv;
    bi = take ? oi : bi;
  }
  int n = bi;
  int kc = n >= NPK ? 1 : 0;
  int ns = n - kc * NPK;
  ns = ns < NQ ? ns : NQ - 1;

  int qy = q / NHW, qx = q - qy * NHW;
  int ny = ns / NHW, nx = ns - ny * NHW;
  const float* P = pred + (size_t)b * CC * HW2;
  const float* T = targ + (size_t)(b * 2 + kc) * CC * HW2;
  float s = 0.f;
  for (int i = lane; i < CC * 9; i += 64) {
    int c = i / 9, sp = i - 9 * c;
    int di = sp / 3, dj = sp - 3 * di;
    float d = P[(size_t)c * HW2 + (qy + di) * WW + qx + dj]
            - T[(size_t)c * HW2 + (ny + di) * WW + nx + dj];
    s += d * d;
  }
  #pragma unroll
  for (int off = 1; off < 64; off <<= 1) s += __shfl_xor(s, off, 64);
  if (lane == 0) msep[gw] = s;
}

// ---- kernel 4: final deterministic reduction ----
__global__ void k_final(const float* __restrict__ msep, float* __restrict__ out) {
  int t = threadIdx.x;
  float s = 0.f;
  for (int i = t; i < BATCH * NQ; i += 256) s += msep[i];
  __shared__ float red[256];
  red[t] = s; __syncthreads();
  for (int st = 128; st > 0; st >>= 1) { if (t < st) red[t] += red[t + st]; __syncthreads(); }
  if (t == 0) out[0] = red[0] * (1.0f / 4875264.0f);   // 2*2116*128*9
}

extern "C" void kernel_launch(void* const* d_in, const int* in_sizes, int n_in,
                              void* d_out, int out_size, void* d_ws, size_t ws_size,
                              hipStream_t stream) {
  const float* pred = (const float*)d_in[0];
  const float* targ = (const float*)d_in[1];
  char* ws = (char*)d_ws;

  size_t offA = 0;
  size_t offB = offA + (size_t)BATCH * MROWS * KK * 2;      // 10,027,008
  size_t offV = offB + (size_t)BATCH * NTOT * KK * 2;       // 20,054,016
  size_t offI = offV + (size_t)BATCH * MROWS * NHALF * 4;   // 1,183,744
  size_t offM = offI + (size_t)BATCH * MROWS * NHALF * 4;   // 1,183,744

  u16*   Ab   = (u16*)(ws + offA);
  u16*   Bb   = (u16*)(ws + offB);
  float* valp = (float*)(ws + offV);
  int*   idxp = (int*)(ws + offI);
  float* msep = (float*)(ws + offM);

  k_im2col<<<dim3(48, 6), 256, 0, stream>>>(pred, targ, Ab, Bb);
  k_gemm<<<dim3(578), 512, 0, stream>>>(Ab, Bb, valp, idxp);
  k_msearg<<<dim3((BATCH * NQ + 3) / 4), 256, 0, stream>>>(pred, targ, valp, idxp, msep);
  k_final<<<1, 256, 0, stream>>>(msep, (float*)d_out);
}